// Round 4
// baseline (374.916 us; speedup 1.0000x reference)
//
#include <hip/hip_runtime.h>

// Decoder: Bahdanau attention + GRU cell + vocab projection
// VOCAB=32000, EMB=512, H=1024, B=64, S=128
// GEMMs via bf16 MFMA (v_mfma_f32_16x16x32_bf16), fp32 accumulate.
// Fragment layouts (learn_hip m89/m91/m120):
//   A: lane holds A[m=lane&15][k=(lane>>4)*8 + j], j=0..7 (8 bf16, b128)
//   B: lane holds B[k=(lane>>4)*8 + j][n=lane&15]
//   C/D: row=(lane>>4)*4+reg, col=lane&15
//
// R4: depth-4 register prefetch for NF=1 GEMMs (probs/dual/xm).
//   R1 probs evidence: 667 GB/s on a pure 131 MB stream = duty-cycle limited
//   (loads in flight only ~30% of each k-step; depth-2 issues loads ~600 cyc
//   before their vmcnt drain < 900 cyc HBM latency). Depth 4 issues ~1200+
//   cyc ahead -> per-set waits return immediately, stream flows.
//   All NF=1 call sites have step-counts divisible by 4 (xm kslice 192->256).
//   Score (NF=4) stays depth-2 (VGPR pressure). LDS protocol unchanged
//   (double buffer, one barrier per 32-k step).

#define B_ 64
#define S_ 128
#define H_ 1024
#define EMB_ 512
#define VOCAB_ 32000

typedef __attribute__((ext_vector_type(8))) short short8;
typedef __attribute__((ext_vector_type(4))) float f32x4;

__device__ __forceinline__ unsigned short f2bf_bits(float f) {
    unsigned int u = __float_as_uint(f);
    u += 0x7FFF + ((u >> 16) & 1);  // round-to-nearest-even
    return (unsigned short)(u >> 16);
}
__device__ __forceinline__ float sigmoidf_(float x) { return 1.0f / (1.0f + expf(-x)); }
// A-tile swizzle key (16B slots within a 64B row of 32 bf16)
__device__ __forceinline__ int sw_(int r) { return (r ^ (r >> 2)) & 3; }
// B-tile swizzle key for col n (16B chunk XOR within [n][32k] row)
__device__ __forceinline__ int bf_(int n) { return (n ^ (n >> 2)) & 3; }
__device__ __forceinline__ float fc4_(const float4& v, int c) {
    return c == 0 ? v.x : c == 1 ? v.y : c == 2 ? v.z : v.w;
}

__device__ __forceinline__ short8 pack8_(float4 lo, float4 hi) {
    short8 s;
    s[0] = (short)f2bf_bits(lo.x);
    s[1] = (short)f2bf_bits(lo.y);
    s[2] = (short)f2bf_bits(lo.z);
    s[3] = (short)f2bf_bits(lo.w);
    s[4] = (short)f2bf_bits(hi.x);
    s[5] = (short)f2bf_bits(hi.y);
    s[6] = (short)f2bf_bits(hi.z);
    s[7] = (short)f2bf_bits(hi.w);
    return s;
}

// ---------------------------------------------------------------------------
// Tile GEMM core: C_tile(64 x 64*NF) += A(64xK slice) * W(K x N) over k0..k1.
// Step count (k1-k0)/32 must be divisible by DEPTH (4 for NF=1, 2 for NF>=2).
// A_lds: [64 m][32 k] bf16, 16B-slot swizzle sw_(row).
// B_lds: [NT n][32 k] bf16, element [n][k] at n*32 + ((k>>3)^bf_(n))*8 + (k&7).
// ---------------------------------------------------------------------------
template <int NF>
__device__ void mfma_gemm_tile(const float* __restrict__ A, int lda,
                               const float* __restrict__ W, int ldw,
                               int m_base, int n_base, int k0, int k1,
                               f32x4 (&acc)[4][NF]) {
    constexpr int NT = 64 * NF;
    constexpr int JOBS = (NF >= 2) ? NF / 2 : 1;
    constexpr int DEPTH = (NF == 1) ? 4 : 2;
    __shared__ __attribute__((aligned(16))) unsigned short A_lds[2][64 * 32];
    __shared__ __attribute__((aligned(16))) unsigned short B_lds[2][NT * 32];
    const int tid = threadIdx.x;
    const int w = tid >> 6, lane = tid & 63, quad = lane >> 4, l15 = lane & 15;

    const f32x4 z = {0.0f, 0.0f, 0.0f, 0.0f};
#pragma unroll
    for (int mi = 0; mi < 4; ++mi)
#pragma unroll
        for (int ni = 0; ni < NF; ++ni) acc[mi][ni] = z;

    // A staging coords: row ar, 16B k-chunk ac
    const int ar = tid >> 2, ac = tid & 3;
    const int aslot = ac ^ sw_(ar);
    // B staging jobs: 4k x 4n blocks (NF>=2) or 4k x 2n (NF==1)
    int bk[JOBS], bn[JOBS];
    if constexpr (NF == 1) {
        bk[0] = 4 * (tid >> 5);  // 0,4,..,28
        bn[0] = 2 * (tid & 31);  // 0,2,..,62
    } else {
#pragma unroll
        for (int j = 0; j < JOBS; ++j) {
            int id = tid + 256 * j;
            bk[j] = 4 * (id / (16 * NF));
            bn[j] = 4 * (id % (16 * NF));
        }
    }

    float4 areg[DEPTH][2];
    float4 br4[DEPTH][JOBS][4];  // NF>=2
    float2 br2[DEPTH][4];        // NF==1

    // ---- prologue: load tile sets 0..DEPTH-1 ----
#pragma unroll
    for (int s = 0; s < DEPTH; ++s) {
        int kk = k0 + 32 * s;
        if (s == 0 || kk < k1) {
            const float* asrc = A + (size_t)(m_base + ar) * lda + kk + 8 * ac;
            areg[s][0] = *(const float4*)asrc;
            areg[s][1] = *(const float4*)(asrc + 4);
            if constexpr (NF == 1) {
                const float* bs = W + (size_t)(kk + bk[0]) * ldw + n_base + bn[0];
#pragma unroll
                for (int i = 0; i < 4; ++i)
                    br2[s][i] = *(const float2*)(bs + (size_t)i * ldw);
            } else {
#pragma unroll
                for (int j = 0; j < JOBS; ++j) {
                    const float* bs = W + (size_t)(kk + bk[j]) * ldw + n_base + bn[j];
#pragma unroll
                    for (int i = 0; i < 4; ++i)
                        br4[s][j][i] = *(const float4*)(bs + (size_t)i * ldw);
                }
            }
        }
    }

    int p = 0;
    for (int k = k0; k < k1; k += 32 * DEPTH) {
#pragma unroll
        for (int s = 0; s < DEPTH; ++s) {
            // ---- convert + write set s -> LDS[p] ----
            *(short8*)&A_lds[p][ar * 32 + aslot * 8] = pack8_(areg[s][0], areg[s][1]);
            if constexpr (NF == 1) {
                const int kb = bk[0];
#pragma unroll
                for (int c = 0; c < 2; ++c) {
                    int n = bn[0] + c;
                    int si = n * 32 + ((((kb >> 3) ^ bf_(n)) << 3) + (kb & 7));
                    unsigned int lo, hi;
                    if (c == 0) {
                        lo = (unsigned)f2bf_bits(br2[s][0].x) |
                             ((unsigned)f2bf_bits(br2[s][1].x) << 16);
                        hi = (unsigned)f2bf_bits(br2[s][2].x) |
                             ((unsigned)f2bf_bits(br2[s][3].x) << 16);
                    } else {
                        lo = (unsigned)f2bf_bits(br2[s][0].y) |
                             ((unsigned)f2bf_bits(br2[s][1].y) << 16);
                        hi = (unsigned)f2bf_bits(br2[s][2].y) |
                             ((unsigned)f2bf_bits(br2[s][3].y) << 16);
                    }
                    uint2 wv;
                    wv.x = lo;
                    wv.y = hi;
                    *(uint2*)&B_lds[p][si] = wv;
                }
            } else {
#pragma unroll
                for (int j = 0; j < JOBS; ++j) {
                    const int kb = bk[j];
#pragma unroll
                    for (int c = 0; c < 4; ++c) {
                        int n = bn[j] + c;
                        int si = n * 32 + ((((kb >> 3) ^ bf_(n)) << 3) + (kb & 7));
                        unsigned int lo = (unsigned)f2bf_bits(fc4_(br4[s][j][0], c)) |
                                          ((unsigned)f2bf_bits(fc4_(br4[s][j][1], c)) << 16);
                        unsigned int hi = (unsigned)f2bf_bits(fc4_(br4[s][j][2], c)) |
                                          ((unsigned)f2bf_bits(fc4_(br4[s][j][3], c)) << 16);
                        uint2 wv;
                        wv.x = lo;
                        wv.y = hi;
                        *(uint2*)&B_lds[p][si] = wv;
                    }
                }
            }
            __syncthreads();
            // ---- prefetch set s <- tile kk + 32*DEPTH ----
            const int kpre = k + 32 * s + 32 * DEPTH;
            if (kpre < k1) {
                const float* asrc = A + (size_t)(m_base + ar) * lda + kpre + 8 * ac;
                areg[s][0] = *(const float4*)asrc;
                areg[s][1] = *(const float4*)(asrc + 4);
                if constexpr (NF == 1) {
                    const float* bs = W + (size_t)(kpre + bk[0]) * ldw + n_base + bn[0];
#pragma unroll
                    for (int i = 0; i < 4; ++i)
                        br2[s][i] = *(const float2*)(bs + (size_t)i * ldw);
                } else {
#pragma unroll
                    for (int j = 0; j < JOBS; ++j) {
                        const float* bs =
                            W + (size_t)(kpre + bk[j]) * ldw + n_base + bn[j];
#pragma unroll
                        for (int i = 0; i < 4; ++i)
                            br4[s][j][i] = *(const float4*)(bs + (size_t)i * ldw);
                    }
                }
            }
            // ---- compute from LDS[p] ----
            short8 bfrag[NF];
#pragma unroll
            for (int ni = 0; ni < NF; ++ni) {
                int nrel = w * 16 * NF + 16 * ni + l15;
                bfrag[ni] =
                    *(const short8*)&B_lds[p][nrel * 32 + ((quad ^ bf_(nrel)) << 3)];
            }
#pragma unroll
            for (int mi = 0; mi < 4; ++mi) {
                int r = 16 * mi + l15;
                short8 afrag =
                    *(const short8*)&A_lds[p][r * 32 + ((quad ^ sw_(r)) << 3)];
#pragma unroll
                for (int ni = 0; ni < NF; ++ni)
                    acc[mi][ni] = __builtin_amdgcn_mfma_f32_16x16x32_bf16(
                        afrag, bfrag[ni], acc[mi][ni], 0, 0, 0);
            }
            p ^= 1;
        }
    }
}

// ---------------------------------------------------------------------------
// Fused bias pre-init for all atomic-accumulate targets.
// ---------------------------------------------------------------------------
__global__ void init_bias4_kernel(float* __restrict__ hproj, const float* __restrict__ W2_b,
                                  float* __restrict__ hm, float* __restrict__ xm,
                                  const float* __restrict__ gru_b,
                                  float* __restrict__ score, const float* __restrict__ V_b) {
    int i = blockIdx.x * 256 + threadIdx.x;
    const int E0 = B_ * H_;
    const int E1 = E0 + B_ * 3 * H_;
    const int E2 = E1 + B_ * 3 * H_;
    const int E3 = E2 + B_ * S_;
    if (i < E0) {
        hproj[i] = W2_b[i & (H_ - 1)];
    } else if (i < E1) {
        int j = i - E0;
        hm[j] = gru_b[3 * H_ + j % (3 * H_)];
    } else if (i < E2) {
        int j = i - E1;
        xm[j] = gru_b[j % (3 * H_)];
    } else if (i < E3) {
        score[i - E2] = V_b[0];
    }
}

// ---------------------------------------------------------------------------
// Skinny GEMM (M=64), K-split across blockIdx.y, atomicAdd into pre-inited C.
// ---------------------------------------------------------------------------
template <int NF>
__global__ __launch_bounds__(256) void gemm_mfma_atomic_kernel(
    const float* __restrict__ A, int lda, const float* __restrict__ W, int ldw,
    float* __restrict__ C, int kslice) {
    f32x4 acc[4][NF];
    const int n_base = blockIdx.x * 64 * NF;
    const int k0 = blockIdx.y * kslice;
    mfma_gemm_tile<NF>(A, lda, W, ldw, 0, n_base, k0, k0 + kslice, acc);
    const int tid = threadIdx.x, w = tid >> 6, lane = tid & 63;
    const int quad = lane >> 4, l15 = lane & 15;
#pragma unroll
    for (int mi = 0; mi < 4; ++mi)
#pragma unroll
        for (int ni = 0; ni < NF; ++ni) {
            int col = n_base + w * 16 * NF + 16 * ni + l15;
#pragma unroll
            for (int r = 0; r < 4; ++r) {
                int row = 16 * mi + quad * 4 + r;
                atomicAdd(&C[(size_t)row * ldw + col], acc[mi][ni][r]);
            }
        }
}

// ---------------------------------------------------------------------------
// Dual skinny GEMM sharing A=hidden: bx<16 -> hproj += hidden@W2_k (N=1024);
// bx>=16 -> hm += hidden@gru_rk (N=3072). K=1024, k-split via blockIdx.y.
// ---------------------------------------------------------------------------
__global__ __launch_bounds__(256) void gemm_dual_kernel(
    const float* __restrict__ hidden, const float* __restrict__ W2_k,
    const float* __restrict__ gru_rk, float* __restrict__ hproj,
    float* __restrict__ hm, int kslice) {
    f32x4 acc[4][1];
    const int bx = blockIdx.x;
    const float* W;
    float* C;
    int ldw, n_base;
    if (bx < 16) {
        W = W2_k; C = hproj; ldw = H_; n_base = bx * 64;
    } else {
        W = gru_rk; C = hm; ldw = 3 * H_; n_base = (bx - 16) * 64;
    }
    const int k0 = blockIdx.y * kslice;
    mfma_gemm_tile<1>(hidden, H_, W, ldw, 0, n_base, k0, k0 + kslice, acc);
    const int tid = threadIdx.x, w = tid >> 6, lane = tid & 63;
    const int quad = lane >> 4, l15 = lane & 15;
#pragma unroll
    for (int mi = 0; mi < 4; ++mi) {
        int col = n_base + w * 16 + l15;
#pragma unroll
        for (int r = 0; r < 4; ++r) {
            int row = 16 * mi + quad * 4 + r;
            atomicAdd(&C[(size_t)row * ldw + col], acc[mi][0][r]);
        }
    }
}

// ---------------------------------------------------------------------------
// score: feat = enc @ W1 (block: 64 (b,s)-rows x 256 feat-cols), then
// partial score = sum_k tanh(feat + W1b[k] + hproj[b][k]) * Vk[k], reduced
// across the 16 lanes sharing a quad, atomicAdd into V_b-pre-inited score.
// ---------------------------------------------------------------------------
__global__ __launch_bounds__(256) void score_mfma_kernel(
    const float* __restrict__ enc, const float* __restrict__ W1,
    const float* __restrict__ W1b, const float* __restrict__ Vk,
    const float* __restrict__ hproj, float* __restrict__ score) {
    f32x4 acc[4][4];
    const int n_base = blockIdx.x * 256;
    const int m_base = blockIdx.y * 64;
    const int b = m_base >> 7, s_base = m_base & 127;
    mfma_gemm_tile<4>(enc, H_, W1, H_, m_base, n_base, 0, H_, acc);

    const int tid = threadIdx.x, w = tid >> 6, lane = tid & 63;
    const int quad = lane >> 4, l15 = lane & 15;

    float rowpart[4][4];
#pragma unroll
    for (int mi = 0; mi < 4; ++mi)
#pragma unroll
        for (int r = 0; r < 4; ++r) rowpart[mi][r] = 0.0f;

#pragma unroll
    for (int ni = 0; ni < 4; ++ni) {
        int kcol = n_base + w * 64 + 16 * ni + l15;
        float add = W1b[kcol] + hproj[(size_t)b * H_ + kcol];
        float vv = Vk[kcol];
#pragma unroll
        for (int mi = 0; mi < 4; ++mi)
#pragma unroll
            for (int r = 0; r < 4; ++r)
                rowpart[mi][r] += tanhf(acc[mi][ni][r] + add) * vv;
    }
#pragma unroll
    for (int m = 1; m <= 8; m <<= 1)
#pragma unroll
        for (int mi = 0; mi < 4; ++mi)
#pragma unroll
            for (int r = 0; r < 4; ++r)
                rowpart[mi][r] += __shfl_xor(rowpart[mi][r], m, 64);
    if (l15 == 0) {
#pragma unroll
        for (int mi = 0; mi < 4; ++mi)
#pragma unroll
            for (int r = 0; r < 4; ++r)
                atomicAdd(&score[b * S_ + s_base + 16 * mi + quad * 4 + r],
                          rowpart[mi][r]);
    }
}

// ---------------------------------------------------------------------------
// probs = state @ out_k + out_b (M=64, N=32000, K=1024), direct store.
// ---------------------------------------------------------------------------
__global__ __launch_bounds__(256) void probs_mfma_kernel(
    const float* __restrict__ state, const float* __restrict__ out_k,
    const float* __restrict__ out_b, float* __restrict__ probs) {
    f32x4 acc[4][1];
    const int n_base = blockIdx.x * 64;
    mfma_gemm_tile<1>(state, H_, out_k, VOCAB_, 0, n_base, 0, H_, acc);
    const int tid = threadIdx.x, w = tid >> 6, lane = tid & 63;
    const int quad = lane >> 4, l15 = lane & 15;
    int col = n_base + w * 16 + l15;
    float bv = out_b[col];
#pragma unroll
    for (int mi = 0; mi < 4; ++mi) {
#pragma unroll
        for (int r = 0; r < 4; ++r) {
            int row = 16 * mi + quad * 4 + r;
            probs[(size_t)row * VOCAB_ + col] = acc[mi][0][r] + bv;
        }
    }
}

// ---------------------------------------------------------------------------
// Fused softmax + context + buildx. Grid 256 = 64 b x 4 q.
// ---------------------------------------------------------------------------
__global__ __launch_bounds__(256) void attn_ctx_kernel(
    const float* __restrict__ score, const float* __restrict__ enc,
    const float* __restrict__ emb, const int* __restrict__ dec,
    float* __restrict__ attn_out, float* __restrict__ xvec) {
    const int b = blockIdx.x >> 2, q = blockIdx.x & 3;
    const int t = threadIdx.x;
    __shared__ float red[128];
    __shared__ float aw[128];
    float v = 0.0f;
    if (t < 128) {
        v = score[b * S_ + t];
        red[t] = v;
    }
    __syncthreads();
    for (int str = 64; str > 0; str >>= 1) {
        if (t < str) red[t] = fmaxf(red[t], red[t + str]);
        __syncthreads();
    }
    float m = red[0];
    __syncthreads();
    float e = 0.0f;
    if (t < 128) {
        e = expf(v - m);
        red[t] = e;
    }
    __syncthreads();
    for (int str = 64; str > 0; str >>= 1) {
        if (t < str) red[t] += red[t + str];
        __syncthreads();
    }
    float inv = 1.0f / red[0];
    if (t < 128) aw[t] = e * inv;
    __syncthreads();

    const int col = q * 256 + t;
    const float* ebase = enc + (size_t)b * S_ * H_ + col;
    float a0 = 0.0f, a1 = 0.0f, a2 = 0.0f, a3 = 0.0f;
    for (int s = 0; s < S_; s += 4) {
        a0 += aw[s + 0] * ebase[(size_t)(s + 0) * H_];
        a1 += aw[s + 1] * ebase[(size_t)(s + 1) * H_];
        a2 += aw[s + 2] * ebase[(size_t)(s + 2) * H_];
        a3 += aw[s + 3] * ebase[(size_t)(s + 3) * H_];
    }
    xvec[(size_t)b * (H_ + EMB_) + col] = (a0 + a1) + (a2 + a3);

    if (q == 0 && t < 128) attn_out[b * S_ + t] = aw[t];
    if (q == 1) {
        int tok = dec[b];
        float* xb = xvec + (size_t)b * (H_ + EMB_) + H_;
        xb[t] = emb[(size_t)tok * EMB_ + t];
        xb[t + 256] = emb[(size_t)tok * EMB_ + t + 256];
    }
}

// ---------------------------------------------------------------------------
// GRU gates: state -> fp32 output region
// ---------------------------------------------------------------------------
__global__ void gates_kernel(const float* __restrict__ xm, const float* __restrict__ hm,
                             const float* __restrict__ hidden,
                             float* __restrict__ state_out) {
    const int idx = blockIdx.x * 256 + threadIdx.x;  // 0..65535
    const int b = idx >> 10, j = idx & (H_ - 1);
    const float* xmb = xm + (size_t)b * 3 * H_;
    const float* hmb = hm + (size_t)b * 3 * H_;
    float z = sigmoidf_(xmb[j] + hmb[j]);
    float r = sigmoidf_(xmb[H_ + j] + hmb[H_ + j]);
    float hc = tanhf(xmb[2 * H_ + j] + r * hmb[2 * H_ + j]);
    state_out[idx] = z * hidden[idx] + (1.0f - z) * hc;
}

// ---------------------------------------------------------------------------
extern "C" void kernel_launch(void* const* d_in, const int* in_sizes, int n_in,
                              void* d_out, int out_size, void* d_ws, size_t ws_size,
                              hipStream_t stream) {
    const int* dec_input = (const int*)d_in[0];
    const float* hidden = (const float*)d_in[1];
    const float* enc = (const float*)d_in[2];
    const float* emb = (const float*)d_in[3];
    const float* W1_k = (const float*)d_in[4];
    const float* W1_b = (const float*)d_in[5];
    const float* W2_k = (const float*)d_in[6];
    const float* W2_b = (const float*)d_in[7];
    const float* V_k = (const float*)d_in[8];
    const float* V_b = (const float*)d_in[9];
    const float* gru_k = (const float*)d_in[10];
    const float* gru_rk = (const float*)d_in[11];
    const float* gru_b = (const float*)d_in[12];
    const float* out_k = (const float*)d_in[13];
    const float* out_b = (const float*)d_in[14];

    float* out = (float*)d_out;
    float* probs_out = out;                              // 64*32000 = 2,048,000 f
    float* state_out = out + (size_t)B_ * VOCAB_;        // 64*1024
    float* attn_out = state_out + (size_t)B_ * H_;       // 64*128

    // Scratch lives in the (dead until step 7) probs output region:
    // hproj 65536 | hm 196608 | score 8192 | xvec 98304 | xm 196608
    // = 565,248 floats < 2,048,000. probs_mfma overwrites the whole region
    // last and reads only state_out/out_k/out_b. d_ws untouched.
    float* hproj = probs_out;
    float* hm = hproj + B_ * H_;
    float* score = hm + B_ * 3 * H_;
    float* xvec = score + B_ * S_;
    float* xm = xvec + B_ * (H_ + EMB_);

    // 1. pre-init accumulators with biases (fused, 1 launch)
    const int INIT_TOTAL = B_ * H_ + 2 * B_ * 3 * H_ + B_ * S_;  // 466944
    init_bias4_kernel<<<(INIT_TOTAL + 255) / 256, 256, 0, stream>>>(
        hproj, W2_b, hm, xm, gru_b, score, V_b);

    // 2. hproj += hidden @ W2_k AND hm += hidden @ gru_rk (fused dual launch)
    //    kslice 128 -> 4 k-steps (DEPTH=4 aligned)
    gemm_dual_kernel<<<dim3(64, 8), 256, 0, stream>>>(hidden, W2_k, gru_rk, hproj,
                                                      hm, H_ / 8);
    // 3. score += fused tanh/V epilogue of enc @ W1  (4 n-tiles x 128 m-tiles)
    score_mfma_kernel<<<dim3(4, 128), 256, 0, stream>>>(enc, W1_k, W1_b, V_k, hproj,
                                                        score);
    // 4. softmax + context + buildx (fused) -> attn_out, xvec
    attn_ctx_kernel<<<B_ * 4, 256, 0, stream>>>(score, enc, emb, dec_input, attn_out,
                                                xvec);
    // 5. xm += x @ gru_k   (48 x 6 -> 288 blocks, kslice 256 = 8 k-steps)
    gemm_mfma_atomic_kernel<1><<<dim3(48, 6), 256, 0, stream>>>(xvec, H_ + EMB_, gru_k,
                                                                3 * H_, xm, 256);
    // 6. gates -> state output region
    gates_kernel<<<(B_ * H_) / 256, 256, 0, stream>>>(xm, hm, hidden, state_out);
    // 7. probs = state @ out_k + out_b  (500 blocks, 32 k-steps, DEPTH=4)
    probs_mfma_kernel<<<dim3(VOCAB_ / 64), 256, 0, stream>>>(state_out, out_k, out_b,
                                                             probs_out);
}

// Round 5
// 367.969 us; speedup vs baseline: 1.0189x; 1.0189x over previous
//
#include <hip/hip_runtime.h>

// Decoder: Bahdanau attention + GRU cell + vocab projection
// VOCAB=32000, EMB=512, H=1024, B=64, S=128
// GEMMs via bf16 MFMA (v_mfma_f32_16x16x32_bf16), fp32 accumulate.
// Fragment layouts (learn_hip m89/m91/m120):
//   A: lane holds A[m=lane&15][k=(lane>>4)*8 + j], j=0..7 (8 bf16, b128)
//   B: lane holds B[k=(lane>>4)*8 + j][n=lane&15]
//   C/D: row=(lane>>4)*4+reg, col=lane&15
//
// R5:
//  - ROOT CAUSE from R4 counters: B-staging writes were ~8-way bank
//    conflicted (SQ_LDS_BANK_CONFLICT = 2^23 saturated in score): with the
//    old n-major lane mapping, write bank degenerated to f(slot) only.
//    New staging job map: (row = tid>>2, slot = tid&3) -> each wave writes
//    rows 0..15 x 4 swizzled 16B slots = full 1KB bank spread, conflict-free.
//  - W1 pre-transposed+converted ONCE to bf16 W1T[n][k] (w1t_kernel);
//    score's B staging is pure short8 copies (was 128x redundant fp32->bf16
//    conversion, ~208 VALU ops/k-step).
//  - score: 1-D grid with XCD swizzle so the 4 n-tiles sharing an enc slice
//    hit the same XCD L2 (enc fetched ~1x not 4x).
//  - NF=1 GEMMs (dual/xm/probs): 8 k-strided scalar B loads + one clean
//    ds_write_b128; depth-4 register prefetch kept.

#define B_ 64
#define S_ 128
#define H_ 1024
#define EMB_ 512
#define VOCAB_ 32000

typedef __attribute__((ext_vector_type(8))) short short8;
typedef __attribute__((ext_vector_type(4))) float f32x4;

__device__ __forceinline__ unsigned short f2bf_bits(float f) {
    unsigned int u = __float_as_uint(f);
    u += 0x7FFF + ((u >> 16) & 1);  // round-to-nearest-even
    return (unsigned short)(u >> 16);
}
__device__ __forceinline__ float sigmoidf_(float x) { return 1.0f / (1.0f + expf(-x)); }
// 16B-slot swizzle key for row r (A and B tiles share the same scheme)
__device__ __forceinline__ int sw_(int r) { return (r ^ (r >> 2)) & 3; }

__device__ __forceinline__ short8 pack8_(float4 lo, float4 hi) {
    short8 s;
    s[0] = (short)f2bf_bits(lo.x);
    s[1] = (short)f2bf_bits(lo.y);
    s[2] = (short)f2bf_bits(lo.z);
    s[3] = (short)f2bf_bits(lo.w);
    s[4] = (short)f2bf_bits(hi.x);
    s[5] = (short)f2bf_bits(hi.y);
    s[6] = (short)f2bf_bits(hi.z);
    s[7] = (short)f2bf_bits(hi.w);
    return s;
}

// ---------------------------------------------------------------------------
// W1T[n][k] = bf16(W1[k][n]), tiled 64x64 transpose via LDS.
// Grid (16 k-tiles, 16 n-tiles), 256 threads.
// ---------------------------------------------------------------------------
__global__ __launch_bounds__(256) void w1t_kernel(const float* __restrict__ W1,
                                                  unsigned short* __restrict__ W1T) {
    __shared__ unsigned short tile[64][72];  // [n][k], stride 144B (16B-aligned)
    const int k0 = blockIdx.x * 64, n0 = blockIdx.y * 64;
    const int t = threadIdx.x;
    const int r = t >> 4, c4 = t & 15;
#pragma unroll
    for (int rr = 0; rr < 64; rr += 16) {
        float4 v = *(const float4*)&W1[(size_t)(k0 + r + rr) * H_ + n0 + 4 * c4];
        tile[4 * c4 + 0][r + rr] = f2bf_bits(v.x);
        tile[4 * c4 + 1][r + rr] = f2bf_bits(v.y);
        tile[4 * c4 + 2][r + rr] = f2bf_bits(v.z);
        tile[4 * c4 + 3][r + rr] = f2bf_bits(v.w);
    }
    __syncthreads();
    const int n = t >> 3, kc = t & 7;
#pragma unroll
    for (int pass = 0; pass < 2; ++pass) {
        int nn = n + 32 * pass;
        short8 s = *(const short8*)&tile[nn][8 * kc];
        *(short8*)&W1T[(size_t)(n0 + nn) * H_ + k0 + 8 * kc] = s;
    }
}

// ---------------------------------------------------------------------------
// tile1: C(64 x 64) += A(64 x Kslice) * W(K x N) over k0..k1 (NF=1 core).
// (k1-k0)/32 divisible by 4. A rows always 0..63 (callers pass offset ptr).
// A_lds/B_lds: [64 r][32 k] bf16, elem [r][k] at r*32 + ((k>>3 ^ sw_(r))<<3) + (k&7).
// Staging writes: (row=tid>>2, slot=tid&3) -> conflict-free b128 per thread.
// Depth-4 register prefetch, one barrier per 32-k step.
// ---------------------------------------------------------------------------
__device__ void mfma_gemm_tile1(const float* __restrict__ A, int lda,
                                const float* __restrict__ W, int ldw,
                                int n_base, int k0, int k1, f32x4 (&acc)[4]) {
    __shared__ __attribute__((aligned(16))) unsigned short A_lds[2][64 * 32];
    __shared__ __attribute__((aligned(16))) unsigned short B_lds[2][64 * 32];
    const int tid = threadIdx.x;
    const int w = tid >> 6, lane = tid & 63, quad = lane >> 4, l15 = lane & 15;

    const f32x4 z = {0.0f, 0.0f, 0.0f, 0.0f};
#pragma unroll
    for (int mi = 0; mi < 4; ++mi) acc[mi] = z;

    const int ar = tid >> 2, ac = tid & 3;  // staging row / 16B slot
    const int aslot = ac ^ sw_(ar);

    float4 areg[4][2];
    float breg[4][8];
#pragma unroll
    for (int s = 0; s < 4; ++s) {
        const int kk = k0 + 32 * s;
        const float* asrc = A + (size_t)ar * lda + kk + 8 * ac;
        areg[s][0] = *(const float4*)asrc;
        areg[s][1] = *(const float4*)(asrc + 4);
        const float* bs = W + (size_t)(kk + 8 * ac) * ldw + n_base + ar;
#pragma unroll
        for (int j = 0; j < 8; ++j) breg[s][j] = bs[(size_t)j * ldw];
    }

    int p = 0;
    for (int k = k0; k < k1; k += 128) {
#pragma unroll
        for (int s = 0; s < 4; ++s) {
            *(short8*)&A_lds[p][ar * 32 + aslot * 8] = pack8_(areg[s][0], areg[s][1]);
            short8 bv;
#pragma unroll
            for (int j = 0; j < 8; ++j) bv[j] = (short)f2bf_bits(breg[s][j]);
            *(short8*)&B_lds[p][ar * 32 + aslot * 8] = bv;
            __syncthreads();
            const int kpre = k + 32 * s + 128;
            if (kpre < k1) {
                const float* asrc = A + (size_t)ar * lda + kpre + 8 * ac;
                areg[s][0] = *(const float4*)asrc;
                areg[s][1] = *(const float4*)(asrc + 4);
                const float* bs = W + (size_t)(kpre + 8 * ac) * ldw + n_base + ar;
#pragma unroll
                for (int j = 0; j < 8; ++j) breg[s][j] = bs[(size_t)j * ldw];
            }
            const int nrel = w * 16 + l15;
            short8 bfrag =
                *(const short8*)&B_lds[p][nrel * 32 + ((quad ^ sw_(nrel)) << 3)];
#pragma unroll
            for (int mi = 0; mi < 4; ++mi) {
                int r = 16 * mi + l15;
                short8 afrag =
                    *(const short8*)&A_lds[p][r * 32 + ((quad ^ sw_(r)) << 3)];
                acc[mi] = __builtin_amdgcn_mfma_f32_16x16x32_bf16(afrag, bfrag,
                                                                  acc[mi], 0, 0, 0);
            }
            p ^= 1;
        }
    }
}

// ---------------------------------------------------------------------------
// tile_bt4: C(64 x 256) += A(64 x 1024) * W1T^T, B pre-converted bf16 [n][k].
// A fp32 (convert on the fly); B staging = pure short8 copies. Depth-2.
// ---------------------------------------------------------------------------
__device__ void mfma_gemm_tile_bt4(const float* __restrict__ A, int lda,
                                   const unsigned short* __restrict__ WT,
                                   int n_base, f32x4 (&acc)[4][4]) {
    __shared__ __attribute__((aligned(16))) unsigned short A_lds[2][64 * 32];
    __shared__ __attribute__((aligned(16))) unsigned short B_lds[2][256 * 32];
    const int tid = threadIdx.x;
    const int w = tid >> 6, lane = tid & 63, quad = lane >> 4, l15 = lane & 15;

    const f32x4 z = {0.0f, 0.0f, 0.0f, 0.0f};
#pragma unroll
    for (int mi = 0; mi < 4; ++mi)
#pragma unroll
        for (int ni = 0; ni < 4; ++ni) acc[mi][ni] = z;

    const int ar = tid >> 2, ac = tid & 3;
    const int aslot = ac ^ sw_(ar);
    const int bn0 = tid >> 2, bc = tid & 3;  // B job: rows bn0+64i, slot bc

    float4 areg[2][2];
    short8 breg[2][4];
#pragma unroll
    for (int s = 0; s < 2; ++s) {
        const int kk = 32 * s;
        const float* asrc = A + (size_t)ar * lda + kk + 8 * ac;
        areg[s][0] = *(const float4*)asrc;
        areg[s][1] = *(const float4*)(asrc + 4);
#pragma unroll
        for (int i = 0; i < 4; ++i) {
            int n = bn0 + 64 * i;
            breg[s][i] =
                *(const short8*)&WT[(size_t)(n_base + n) * H_ + kk + 8 * bc];
        }
    }

    int p = 0;
    for (int k = 0; k < 1024; k += 64) {
#pragma unroll
        for (int s = 0; s < 2; ++s) {
            *(short8*)&A_lds[p][ar * 32 + aslot * 8] = pack8_(areg[s][0], areg[s][1]);
#pragma unroll
            for (int i = 0; i < 4; ++i) {
                int n = bn0 + 64 * i;
                *(short8*)&B_lds[p][n * 32 + ((bc ^ sw_(n)) << 3)] = breg[s][i];
            }
            __syncthreads();
            const int kpre = k + 32 * s + 64;
            if (kpre < 1024) {
                const float* asrc = A + (size_t)ar * lda + kpre + 8 * ac;
                areg[s][0] = *(const float4*)asrc;
                areg[s][1] = *(const float4*)(asrc + 4);
#pragma unroll
                for (int i = 0; i < 4; ++i) {
                    int n = bn0 + 64 * i;
                    breg[s][i] =
                        *(const short8*)&WT[(size_t)(n_base + n) * H_ + kpre + 8 * bc];
                }
            }
            short8 bfrag[4];
#pragma unroll
            for (int ni = 0; ni < 4; ++ni) {
                int nrel = w * 64 + 16 * ni + l15;
                bfrag[ni] =
                    *(const short8*)&B_lds[p][nrel * 32 + ((quad ^ sw_(nrel)) << 3)];
            }
#pragma unroll
            for (int mi = 0; mi < 4; ++mi) {
                int r = 16 * mi + l15;
                short8 afrag =
                    *(const short8*)&A_lds[p][r * 32 + ((quad ^ sw_(r)) << 3)];
#pragma unroll
                for (int ni = 0; ni < 4; ++ni)
                    acc[mi][ni] = __builtin_amdgcn_mfma_f32_16x16x32_bf16(
                        afrag, bfrag[ni], acc[mi][ni], 0, 0, 0);
            }
            p ^= 1;
        }
    }
}

// ---------------------------------------------------------------------------
// Fused bias pre-init for all atomic-accumulate targets.
// ---------------------------------------------------------------------------
__global__ void init_bias4_kernel(float* __restrict__ hproj, const float* __restrict__ W2_b,
                                  float* __restrict__ hm, float* __restrict__ xm,
                                  const float* __restrict__ gru_b,
                                  float* __restrict__ score, const float* __restrict__ V_b) {
    int i = blockIdx.x * 256 + threadIdx.x;
    const int E0 = B_ * H_;
    const int E1 = E0 + B_ * 3 * H_;
    const int E2 = E1 + B_ * 3 * H_;
    const int E3 = E2 + B_ * S_;
    if (i < E0) {
        hproj[i] = W2_b[i & (H_ - 1)];
    } else if (i < E1) {
        int j = i - E0;
        hm[j] = gru_b[3 * H_ + j % (3 * H_)];
    } else if (i < E2) {
        int j = i - E1;
        xm[j] = gru_b[j % (3 * H_)];
    } else if (i < E3) {
        score[i - E2] = V_b[0];
    }
}

// ---------------------------------------------------------------------------
// Skinny GEMM (M=64), K-split across blockIdx.y, atomicAdd into pre-inited C.
// ---------------------------------------------------------------------------
__global__ __launch_bounds__(256) void gemm_xm_kernel(
    const float* __restrict__ A, int lda, const float* __restrict__ W, int ldw,
    float* __restrict__ C, int kslice) {
    f32x4 acc[4];
    const int n_base = blockIdx.x * 64;
    const int k0 = blockIdx.y * kslice;
    mfma_gemm_tile1(A, lda, W, ldw, n_base, k0, k0 + kslice, acc);
    const int tid = threadIdx.x, w = tid >> 6, lane = tid & 63;
    const int quad = lane >> 4, l15 = lane & 15;
    const int col = n_base + w * 16 + l15;
#pragma unroll
    for (int mi = 0; mi < 4; ++mi)
#pragma unroll
        for (int r = 0; r < 4; ++r) {
            int row = 16 * mi + quad * 4 + r;
            atomicAdd(&C[(size_t)row * ldw + col], acc[mi][r]);
        }
}

// ---------------------------------------------------------------------------
// Dual skinny GEMM sharing A=hidden: bx<16 -> hproj += hidden@W2_k (N=1024);
// bx>=16 -> hm += hidden@gru_rk (N=3072). K-split via blockIdx.y (kslice 128).
// ---------------------------------------------------------------------------
__global__ __launch_bounds__(256) void gemm_dual_kernel(
    const float* __restrict__ hidden, const float* __restrict__ W2_k,
    const float* __restrict__ gru_rk, float* __restrict__ hproj,
    float* __restrict__ hm, int kslice) {
    f32x4 acc[4];
    const int bx = blockIdx.x;
    const float* W;
    float* C;
    int ldw, n_base;
    if (bx < 16) {
        W = W2_k; C = hproj; ldw = H_; n_base = bx * 64;
    } else {
        W = gru_rk; C = hm; ldw = 3 * H_; n_base = (bx - 16) * 64;
    }
    const int k0 = blockIdx.y * kslice;
    mfma_gemm_tile1(hidden, H_, W, ldw, n_base, k0, k0 + kslice, acc);
    const int tid = threadIdx.x, w = tid >> 6, lane = tid & 63;
    const int quad = lane >> 4, l15 = lane & 15;
    const int col = n_base + w * 16 + l15;
#pragma unroll
    for (int mi = 0; mi < 4; ++mi)
#pragma unroll
        for (int r = 0; r < 4; ++r) {
            int row = 16 * mi + quad * 4 + r;
            atomicAdd(&C[(size_t)row * ldw + col], acc[mi][r]);
        }
}

// ---------------------------------------------------------------------------
// score: feat = enc @ W1 (block: 64 (b,s)-rows x 256 feat-cols, W1T bf16),
// then partial score = sum_k tanh(feat + W1b[k] + hproj[b][k]) * Vk[k],
// quad-group shuffle reduce, atomicAdd into V_b-pre-inited score.
// 1-D grid 512 with XCD swizzle: the 4 n-tiles of one m-tile share an XCD L2.
// ---------------------------------------------------------------------------
__global__ __launch_bounds__(256) void score_mfma_kernel(
    const float* __restrict__ enc, const unsigned short* __restrict__ W1T,
    const float* __restrict__ W1b, const float* __restrict__ Vk,
    const float* __restrict__ hproj, float* __restrict__ score) {
    f32x4 acc[4][4];
    const int bid = blockIdx.x;
    const int swz = (bid & 7) * 64 + (bid >> 3);  // 512 blocks, bijective
    const int n_base = (swz & 3) * 256;
    const int m_base = (swz >> 2) * 64;
    const int b = m_base >> 7, s_base = m_base & 127;
    mfma_gemm_tile_bt4(enc + (size_t)m_base * H_, H_, W1T, n_base, acc);

    const int tid = threadIdx.x, w = tid >> 6, lane = tid & 63;
    const int quad = lane >> 4, l15 = lane & 15;

    float rowpart[4][4];
#pragma unroll
    for (int mi = 0; mi < 4; ++mi)
#pragma unroll
        for (int r = 0; r < 4; ++r) rowpart[mi][r] = 0.0f;

#pragma unroll
    for (int ni = 0; ni < 4; ++ni) {
        int kcol = n_base + w * 64 + 16 * ni + l15;
        float add = W1b[kcol] + hproj[(size_t)b * H_ + kcol];
        float vv = Vk[kcol];
#pragma unroll
        for (int mi = 0; mi < 4; ++mi)
#pragma unroll
            for (int r = 0; r < 4; ++r)
                rowpart[mi][r] += tanhf(acc[mi][ni][r] + add) * vv;
    }
#pragma unroll
    for (int m = 1; m <= 8; m <<= 1)
#pragma unroll
        for (int mi = 0; mi < 4; ++mi)
#pragma unroll
            for (int r = 0; r < 4; ++r)
                rowpart[mi][r] += __shfl_xor(rowpart[mi][r], m, 64);
    if (l15 == 0) {
#pragma unroll
        for (int mi = 0; mi < 4; ++mi)
#pragma unroll
            for (int r = 0; r < 4; ++r)
                atomicAdd(&score[b * S_ + s_base + 16 * mi + quad * 4 + r],
                          rowpart[mi][r]);
    }
}

// ---------------------------------------------------------------------------
// probs = state @ out_k + out_b (M=64, N=32000, K=1024), direct store.
// ---------------------------------------------------------------------------
__global__ __launch_bounds__(256) void probs_mfma_kernel(
    const float* __restrict__ state, const float* __restrict__ out_k,
    const float* __restrict__ out_b, float* __restrict__ probs) {
    f32x4 acc[4];
    const int n_base = blockIdx.x * 64;
    mfma_gemm_tile1(state, H_, out_k, VOCAB_, n_base, 0, H_, acc);
    const int tid = threadIdx.x, w = tid >> 6, lane = tid & 63;
    const int quad = lane >> 4, l15 = lane & 15;
    const int col = n_base + w * 16 + l15;
    float bv = out_b[col];
#pragma unroll
    for (int mi = 0; mi < 4; ++mi)
#pragma unroll
        for (int r = 0; r < 4; ++r) {
            int row = 16 * mi + quad * 4 + r;
            probs[(size_t)row * VOCAB_ + col] = acc[mi][r] + bv;
        }
}

// ---------------------------------------------------------------------------
// Fused softmax + context + buildx. Grid 256 = 64 b x 4 q.
// ---------------------------------------------------------------------------
__global__ __launch_bounds__(256) void attn_ctx_kernel(
    const float* __restrict__ score, const float* __restrict__ enc,
    const float* __restrict__ emb, const int* __restrict__ dec,
    float* __restrict__ attn_out, float* __restrict__ xvec) {
    const int b = blockIdx.x >> 2, q = blockIdx.x & 3;
    const int t = threadIdx.x;
    __shared__ float red[128];
    __shared__ float aw[128];
    float v = 0.0f;
    if (t < 128) {
        v = score[b * S_ + t];
        red[t] = v;
    }
    __syncthreads();
    for (int str = 64; str > 0; str >>= 1) {
        if (t < str) red[t] = fmaxf(red[t], red[t + str]);
        __syncthreads();
    }
    float m = red[0];
    __syncthreads();
    float e = 0.0f;
    if (t < 128) {
        e = expf(v - m);
        red[t] = e;
    }
    __syncthreads();
    for (int str = 64; str > 0; str >>= 1) {
        if (t < str) red[t] += red[t + str];
        __syncthreads();
    }
    float inv = 1.0f / red[0];
    if (t < 128) aw[t] = e * inv;
    __syncthreads();

    const int col = q * 256 + t;
    const float* ebase = enc + (size_t)b * S_ * H_ + col;
    float a0 = 0.0f, a1 = 0.0f, a2 = 0.0f, a3 = 0.0f;
    for (int s = 0; s < S_; s += 4) {
        a0 += aw[s + 0] * ebase[(size_t)(s + 0) * H_];
        a1 += aw[s + 1] * ebase[(size_t)(s + 1) * H_];
        a2 += aw[s + 2] * ebase[(size_t)(s + 2) * H_];
        a3 += aw[s + 3] * ebase[(size_t)(s + 3) * H_];
    }
    xvec[(size_t)b * (H_ + EMB_) + col] = (a0 + a1) + (a2 + a3);

    if (q == 0 && t < 128) attn_out[b * S_ + t] = aw[t];
    if (q == 1) {
        int tok = dec[b];
        float* xb = xvec + (size_t)b * (H_ + EMB_) + H_;
        xb[t] = emb[(size_t)tok * EMB_ + t];
        xb[t + 256] = emb[(size_t)tok * EMB_ + t + 256];
    }
}

// ---------------------------------------------------------------------------
// GRU gates: state -> fp32 output region
// ---------------------------------------------------------------------------
__global__ void gates_kernel(const float* __restrict__ xm, const float* __restrict__ hm,
                             const float* __restrict__ hidden,
                             float* __restrict__ state_out) {
    const int idx = blockIdx.x * 256 + threadIdx.x;  // 0..65535
    const int b = idx >> 10, j = idx & (H_ - 1);
    const float* xmb = xm + (size_t)b * 3 * H_;
    const float* hmb = hm + (size_t)b * 3 * H_;
    float z = sigmoidf_(xmb[j] + hmb[j]);
    float r = sigmoidf_(xmb[H_ + j] + hmb[H_ + j]);
    float hc = tanhf(xmb[2 * H_ + j] + r * hmb[2 * H_ + j]);
    state_out[idx] = z * hidden[idx] + (1.0f - z) * hc;
}

// ---------------------------------------------------------------------------
extern "C" void kernel_launch(void* const* d_in, const int* in_sizes, int n_in,
                              void* d_out, int out_size, void* d_ws, size_t ws_size,
                              hipStream_t stream) {
    const int* dec_input = (const int*)d_in[0];
    const float* hidden = (const float*)d_in[1];
    const float* enc = (const float*)d_in[2];
    const float* emb = (const float*)d_in[3];
    const float* W1_k = (const float*)d_in[4];
    const float* W1_b = (const float*)d_in[5];
    const float* W2_k = (const float*)d_in[6];
    const float* W2_b = (const float*)d_in[7];
    const float* V_k = (const float*)d_in[8];
    const float* V_b = (const float*)d_in[9];
    const float* gru_k = (const float*)d_in[10];
    const float* gru_rk = (const float*)d_in[11];
    const float* gru_b = (const float*)d_in[12];
    const float* out_k = (const float*)d_in[13];
    const float* out_b = (const float*)d_in[14];

    float* out = (float*)d_out;
    float* probs_out = out;                              // 64*32000 = 2,048,000 f
    float* state_out = out + (size_t)B_ * VOCAB_;        // 64*1024
    float* attn_out = state_out + (size_t)B_ * H_;       // 64*128

    // Scratch lives in the (dead until the last kernel) probs output region:
    // hproj 65536 | hm 196608 | score 8192 | xvec 98304 | xm 196608 |
    // W1T 1Mi ushort (524288 f-equiv) = 1,089,536 floats < 2,048,000.
    // probs_mfma overwrites the whole region last. d_ws untouched.
    float* hproj = probs_out;
    float* hm = hproj + B_ * H_;
    float* score = hm + B_ * 3 * H_;
    float* xvec = score + B_ * S_;
    float* xm = xvec + B_ * (H_ + EMB_);
    unsigned short* W1T = (unsigned short*)(xm + B_ * 3 * H_);  // 16B-aligned

    // 1. W1 -> bf16 transposed [n][k] (once; removes 128x redundant convert)
    w1t_kernel<<<dim3(16, 16), 256, 0, stream>>>(W1_k, W1T);

    // 2. pre-init accumulators with biases (fused, 1 launch)
    const int INIT_TOTAL = B_ * H_ + 2 * B_ * 3 * H_ + B_ * S_;  // 466944
    init_bias4_kernel<<<(INIT_TOTAL + 255) / 256, 256, 0, stream>>>(
        hproj, W2_b, hm, xm, gru_b, score, V_b);

    // 3. hproj += hidden @ W2_k AND hm += hidden @ gru_rk (dual, kslice 128)
    gemm_dual_kernel<<<dim3(64, 8), 256, 0, stream>>>(hidden, W2_k, gru_rk, hproj,
                                                      hm, H_ / 8);
    // 4. score += fused tanh/V epilogue of enc @ W1 (512 blocks, XCD-swizzled)
    score_mfma_kernel<<<512, 256, 0, stream>>>(enc, W1T, W1_b, V_k, hproj, score);
    // 5. softmax + context + buildx (fused) -> attn_out, xvec
    attn_ctx_kernel<<<B_ * 4, 256, 0, stream>>>(score, enc, emb, dec_input, attn_out,
                                                xvec);
    // 6. xm += x @ gru_k   (48 x 6 blocks, kslice 256 = 8 k-steps)
    gemm_xm_kernel<<<dim3(48, 6), 256, 0, stream>>>(xvec, H_ + EMB_, gru_k, 3 * H_,
                                                    xm, 256);
    // 7. gates -> state output region
    gates_kernel<<<(B_ * H_) / 256, 256, 0, stream>>>(xm, hm, hidden, state_out);
    // 8. probs = state @ out_k + out_b  (500 blocks, 32 k-steps)
    probs_mfma_kernel<<<dim3(VOCAB_ / 64), 256, 0, stream>>>(state_out, out_k, out_b,
                                                             probs_out);
}